// Round 2
// baseline (542.154 us; speedup 1.0000x reference)
//
#include <hip/hip_runtime.h>
#include <math.h>

#define N_NODES 50000
#define N_EDGES 800000
#define E_TOT   (N_EDGES + N_NODES)
#define HEADS   8
#define OUTC    10
#define HID     80
#define NEG_SLOPE 0.2f

// ---------------- CSR build ----------------

__global__ __launch_bounds__(256) void hist_k(const int* __restrict__ ei, int* __restrict__ cnt) {
    int e = blockIdx.x * blockDim.x + threadIdx.x;
    if (e >= E_TOT) return;
    int d = (e < N_EDGES) ? ei[N_EDGES + e] : (e - N_EDGES);
    atomicAdd(&cnt[d], 1);
}

__global__ __launch_bounds__(1024) void scan_k(const int* __restrict__ cnt, int* __restrict__ rowptr) {
    __shared__ int wsum[16];
    __shared__ int carry_s;
    const int tid = threadIdx.x;
    const int lane = tid & 63, wid = tid >> 6;
    if (tid == 0) carry_s = 0;
    __syncthreads();
    for (int base = 0; base < N_NODES; base += 1024) {
        int i = base + tid;
        int v = (i < N_NODES) ? cnt[i] : 0;
        int s = v;
        #pragma unroll
        for (int off = 1; off < 64; off <<= 1) {
            int t = __shfl_up(s, off, 64);
            if (lane >= off) s += t;
        }
        if (lane == 63) wsum[wid] = s;
        int carry = carry_s;
        __syncthreads();
        if (wid == 0 && lane < 16) {
            int w = wsum[lane];
            #pragma unroll
            for (int off = 1; off < 16; off <<= 1) {
                int t = __shfl_up(w, off, 16);
                if (lane >= off) w += t;
            }
            wsum[lane] = w;  // inclusive scan of wave sums
        }
        __syncthreads();
        int woff = (wid > 0) ? wsum[wid - 1] : 0;
        int incl = s + woff;
        int excl = incl - v;
        if (i < N_NODES) rowptr[i] = carry + excl;
        int total = wsum[15];
        __syncthreads();
        if (tid == 0) carry_s = carry + total;
        __syncthreads();
    }
    if (tid == 0) rowptr[N_NODES] = carry_s;
}

__global__ __launch_bounds__(256) void scatter_k(const int* __restrict__ ei,
                                                 const int* __restrict__ rowptr,
                                                 int* __restrict__ cursor,
                                                 int* __restrict__ csr) {
    int e = blockIdx.x * blockDim.x + threadIdx.x;
    if (e >= E_TOT) return;
    int s, d;
    if (e < N_EDGES) { s = ei[e]; d = ei[N_EDGES + e]; }
    else { s = e - N_EDGES; d = s; }
    int pos = rowptr[d] + atomicAdd(&cursor[d], 1);
    csr[pos] = s;
}

// ---------------- fused dual GEMM: xl = A@Wl, xr = A@Wr ----------------
// A: [n, K] fp32; Wl/Wr: [K, 80]. Block: 64 rows x 160 virtual cols, 256 thr,
// each thread 4 rows x 10 cols. K tiled by 32 (zero-padded remainder).

#define KC 32
__global__ __launch_bounds__(256) void gemm_k(const float* __restrict__ A, int K,
                                              const float* __restrict__ Wl,
                                              const float* __restrict__ Wr,
                                              float* __restrict__ xl,
                                              float* __restrict__ xr) {
    __shared__ float sa[64][KC + 1];
    __shared__ float sw[KC][160];
    const int tid = threadIdx.x;
    const int rg = tid & 15;   // row group: rows rg*4 .. rg*4+3
    const int cg = tid >> 4;   // col group: cols cg*10 .. cg*10+9 (0..15)
    const int row0 = blockIdx.x * 64;

    float acc[4][10];
    #pragma unroll
    for (int r = 0; r < 4; ++r)
        #pragma unroll
        for (int j = 0; j < 10; ++j) acc[r][j] = 0.f;

    for (int kb = 0; kb < K; kb += KC) {
        // A tile: 64 rows x 32 k = 512 float4 loads
        #pragma unroll
        for (int it = 0; it < 2; ++it) {
            int idx = tid + it * 256;
            int r = idx >> 3, k4 = idx & 7;
            int grow = row0 + r, gk = kb + k4 * 4;
            float4 v = make_float4(0.f, 0.f, 0.f, 0.f);
            if (grow < N_NODES && gk < K)
                v = *reinterpret_cast<const float4*>(A + (size_t)grow * K + gk);
            sa[r][k4 * 4 + 0] = v.x; sa[r][k4 * 4 + 1] = v.y;
            sa[r][k4 * 4 + 2] = v.z; sa[r][k4 * 4 + 3] = v.w;
        }
        // W tile: 32 k x 160 cols = 1280 float4 loads
        for (int idx = tid; idx < KC * 40; idx += 256) {
            int k = idx / 40, c4 = idx % 40;
            int gk = kb + k, c = c4 * 4;
            float4 v = make_float4(0.f, 0.f, 0.f, 0.f);
            if (gk < K) {
                if (c < 80) v = *reinterpret_cast<const float4*>(Wl + (size_t)gk * 80 + c);
                else        v = *reinterpret_cast<const float4*>(Wr + (size_t)gk * 80 + (c - 80));
            }
            sw[k][c + 0] = v.x; sw[k][c + 1] = v.y; sw[k][c + 2] = v.z; sw[k][c + 3] = v.w;
        }
        __syncthreads();
        #pragma unroll 4
        for (int k = 0; k < KC; ++k) {
            float a0 = sa[rg * 4 + 0][k];
            float a1 = sa[rg * 4 + 1][k];
            float a2 = sa[rg * 4 + 2][k];
            float a3 = sa[rg * 4 + 3][k];
            #pragma unroll
            for (int j = 0; j < 10; ++j) {
                float w = sw[k][cg * 10 + j];
                acc[0][j] = fmaf(a0, w, acc[0][j]);
                acc[1][j] = fmaf(a1, w, acc[1][j]);
                acc[2][j] = fmaf(a2, w, acc[2][j]);
                acc[3][j] = fmaf(a3, w, acc[3][j]);
            }
        }
        __syncthreads();
    }
    const int c = cg * 10;
    float* basep = (c < 80) ? xl : xr;
    const int cc = (c < 80) ? c : (c - 80);
    #pragma unroll
    for (int r = 0; r < 4; ++r) {
        int grow = row0 + rg * 4 + r;
        if (grow >= N_NODES) continue;
        float* dstp = basep + (size_t)grow * HID + cc;
        #pragma unroll
        for (int j = 0; j < 10; ++j) dstp[j] = acc[r][j];
    }
}

// ---------------- per-node online-softmax aggregation ----------------
// one wave per node; 4 edge slots x 16 lanes; lane u owns channels u*5..u*5+4
// (head h = u>>1). Head logit closed with shfl_xor(1); slots merged flash-style.

__global__ __launch_bounds__(256) void agg_k(const float* __restrict__ xl,
                                             const float* __restrict__ xr,
                                             const int* __restrict__ rowptr,
                                             const int* __restrict__ csr,
                                             const float* __restrict__ att,
                                             const float* __restrict__ bias,
                                             float* __restrict__ out) {
    const int tid = threadIdx.x;
    const int lane = tid & 63;
    const int node = blockIdx.x * 4 + (tid >> 6);
    if (node >= N_NODES) return;
    const int g = lane >> 4;
    const int u = lane & 15;
    const int cb = u * 5;

    float att5[5], xr5[5];
    #pragma unroll
    for (int c = 0; c < 5; ++c) {
        att5[c] = att[cb + c];
        xr5[c] = xr[(size_t)node * HID + cb + c];
    }
    const int ro = rowptr[node];
    const int deg = rowptr[node + 1] - ro;

    float m = -INFINITY, s = 0.f;
    float acc[5] = {0.f, 0.f, 0.f, 0.f, 0.f};

    for (int i = g; i < deg; i += 4) {
        const int src = csr[ro + i];
        const float* xlp = xl + (size_t)src * HID + cb;
        float xl5[5];
        float part = 0.f;
        #pragma unroll
        for (int c = 0; c < 5; ++c) {
            xl5[c] = xlp[c];
            float e = xl5[c] + xr5[c];
            e = (e > 0.f) ? e : NEG_SLOPE * e;
            part = fmaf(e, att5[c], part);
        }
        const float logit = part + __shfl_xor(part, 1, 64);
        const float nm = fmaxf(m, logit);
        const float scale = __expf(m - nm);      // m=-inf -> 0
        const float p = __expf(logit - nm);
        s = s * scale + p;
        #pragma unroll
        for (int c = 0; c < 5; ++c) acc[c] = acc[c] * scale + p * xl5[c];
        m = nm;
    }

    // merge the 4 edge slots (flash-attention state merge)
    #pragma unroll
    for (int off = 16; off <= 32; off <<= 1) {
        const float om = __shfl_xor(m, off, 64);
        const float os = __shfl_xor(s, off, 64);
        float oacc[5];
        #pragma unroll
        for (int c = 0; c < 5; ++c) oacc[c] = __shfl_xor(acc[c], off, 64);
        const float nm = fmaxf(m, om);
        const float sc1 = (m == -INFINITY) ? 0.f : __expf(m - nm);
        const float sc2 = (om == -INFINITY) ? 0.f : __expf(om - nm);
        s = s * sc1 + os * sc2;
        #pragma unroll
        for (int c = 0; c < 5; ++c) acc[c] = acc[c] * sc1 + oacc[c] * sc2;
        m = nm;
    }

    if (g == 0) {
        const float inv = 1.f / (s + 1e-16f);
        #pragma unroll
        for (int c = 0; c < 5; ++c) {
            float v = acc[c] * inv + bias[cb + c];
            v = (v > 0.f) ? v : (__expf(v) - 1.f);   // ELU
            out[(size_t)node * HID + cb + c] = v;
        }
    }
}

// ---------------- launch ----------------

extern "C" void kernel_launch(void* const* d_in, const int* in_sizes, int n_in,
                              void* d_out, int out_size, void* d_ws, size_t ws_size,
                              hipStream_t stream) {
    const float* x  = (const float*)d_in[0];
    const int*   ei = (const int*)d_in[1];
    const float* Wl[3]   = {(const float*)d_in[2], (const float*)d_in[6],  (const float*)d_in[10]};
    const float* Wr[3]   = {(const float*)d_in[3], (const float*)d_in[7],  (const float*)d_in[11]};
    const float* attp[3] = {(const float*)d_in[4], (const float*)d_in[8],  (const float*)d_in[12]};
    const float* bp[3]   = {(const float*)d_in[5], (const float*)d_in[9],  (const float*)d_in[13]};

    char* ws = (char*)d_ws;
    size_t off = 0;
    auto alloc = [&](size_t bytes) -> void* {
        void* p = ws + off;
        off += (bytes + 255) & ~(size_t)255;
        return p;
    };
    int* cnt    = (int*)alloc((size_t)N_NODES * 4);
    int* cursor = (int*)alloc((size_t)N_NODES * 4);
    int* rowptr = (int*)alloc((size_t)(N_NODES + 1) * 4);
    int* csr    = (int*)alloc((size_t)E_TOT * 4);
    float* xl   = (float*)alloc((size_t)N_NODES * HID * 4);
    float* xr   = (float*)alloc((size_t)N_NODES * HID * 4);
    float* actA = (float*)alloc((size_t)N_NODES * HID * 4);
    float* actB = (float*)alloc((size_t)N_NODES * HID * 4);

    hipMemsetAsync(cnt, 0, (size_t)N_NODES * 4, stream);
    hipMemsetAsync(cursor, 0, (size_t)N_NODES * 4, stream);

    hist_k<<<(E_TOT + 255) / 256, 256, 0, stream>>>(ei, cnt);
    scan_k<<<1, 1024, 0, stream>>>(cnt, rowptr);
    scatter_k<<<(E_TOT + 255) / 256, 256, 0, stream>>>(ei, rowptr, cursor, csr);

    for (int l = 0; l < 3; ++l) {
        const float* act_in = (l == 0) ? x : (l == 1 ? actA : actB);
        const int K = (l == 0) ? 256 : 80;
        gemm_k<<<(N_NODES + 63) / 64, 256, 0, stream>>>(act_in, K, Wl[l], Wr[l], xl, xr);
        float* out_l = (l == 0) ? actA : (l == 1 ? actB : (float*)d_out);
        agg_k<<<N_NODES / 4, 256, 0, stream>>>(xl, xr, rowptr, csr, attp[l], bp[l], out_l);
    }
}

// Round 4
// 506.232 us; speedup vs baseline: 1.0710x; 1.0710x over previous
//
#include <hip/hip_runtime.h>
#include <math.h>

#define N_NODES 50000
#define N_EDGES 800000
#define E_TOT   (N_EDGES + N_NODES)
#define HEADS   8
#define OUTC    10
#define HID     80
#define NEG_SLOPE 0.2f

// ---------------- CSR build ----------------

__global__ __launch_bounds__(256) void hist_k(const int* __restrict__ ei, int* __restrict__ cnt) {
    int e = blockIdx.x * blockDim.x + threadIdx.x;
    if (e >= E_TOT) return;
    int d = (e < N_EDGES) ? ei[N_EDGES + e] : (e - N_EDGES);
    atomicAdd(&cnt[d], 1);
}

__global__ __launch_bounds__(1024) void scan_k(const int* __restrict__ cnt, int* __restrict__ rowptr) {
    __shared__ int wsum[16];
    __shared__ int carry_s;
    const int tid = threadIdx.x;
    const int lane = tid & 63, wid = tid >> 6;
    if (tid == 0) carry_s = 0;
    __syncthreads();
    for (int base = 0; base < N_NODES; base += 1024) {
        int i = base + tid;
        int v = (i < N_NODES) ? cnt[i] : 0;
        int s = v;
        #pragma unroll
        for (int off = 1; off < 64; off <<= 1) {
            int t = __shfl_up(s, off, 64);
            if (lane >= off) s += t;
        }
        if (lane == 63) wsum[wid] = s;
        int carry = carry_s;
        __syncthreads();
        if (wid == 0 && lane < 16) {
            int w = wsum[lane];
            #pragma unroll
            for (int off = 1; off < 16; off <<= 1) {
                int t = __shfl_up(w, off, 16);
                if (lane >= off) w += t;
            }
            wsum[lane] = w;  // inclusive scan of wave sums
        }
        __syncthreads();
        int woff = (wid > 0) ? wsum[wid - 1] : 0;
        int incl = s + woff;
        int excl = incl - v;
        if (i < N_NODES) rowptr[i] = carry + excl;
        int total = wsum[15];
        __syncthreads();
        if (tid == 0) carry_s = carry + total;
        __syncthreads();
    }
    if (tid == 0) rowptr[N_NODES] = carry_s;
}

__global__ __launch_bounds__(256) void scatter_k(const int* __restrict__ ei,
                                                 const int* __restrict__ rowptr,
                                                 int* __restrict__ cursor,
                                                 int* __restrict__ csr) {
    int e = blockIdx.x * blockDim.x + threadIdx.x;
    if (e >= E_TOT) return;
    int s, d;
    if (e < N_EDGES) { s = ei[e]; d = ei[N_EDGES + e]; }
    else { s = e - N_EDGES; d = s; }
    int pos = rowptr[d] + atomicAdd(&cursor[d], 1);
    csr[pos] = s;
}

// ---------------- no-LDS dual GEMM: xl = A@Wl, xr = A@Wr ----------------
// Lane = one A row (global/L1-streamed). Wave = 20 output columns, W read with
// wave-uniform addresses (scalarizes to s_load / broadcast VMEM). No LDS, no
// barriers. Block = 4 waves = 80 cols of one W matrix; grid = 1564 blocks.

#define TC 20
__global__ __launch_bounds__(256) void gemm2_k(const float* __restrict__ A, int K,
                                               const float* __restrict__ Wl,
                                               const float* __restrict__ Wr,
                                               float* __restrict__ xl,
                                               float* __restrict__ xr) {
    const int lane = threadIdx.x & 63;
    const int wv = __builtin_amdgcn_readfirstlane(threadIdx.x >> 6);
    const int rg = blockIdx.x >> 1;   // row group (64 rows)
    const int cb = blockIdx.x & 1;    // 0 -> Wl/xl, 1 -> Wr/xr
    const int row = rg * 64 + lane;
    const int j0 = wv * TC;

    const float* __restrict__ W = cb ? Wr : Wl;
    float* __restrict__ Xo = cb ? xr : xl;

    const int r = (row < N_NODES) ? row : (N_NODES - 1);
    const float* __restrict__ Ar = A + (size_t)r * K;

    float acc[TC];
    #pragma unroll
    for (int j = 0; j < TC; ++j) acc[j] = 0.f;

    for (int kb = 0; kb < K; kb += 4) {
        const float4 a = *reinterpret_cast<const float4*>(Ar + kb);
        #pragma unroll
        for (int t = 0; t < 4; ++t) {
            const float av = (t == 0) ? a.x : (t == 1) ? a.y : (t == 2) ? a.z : a.w;
            const float* __restrict__ wrow = W + (size_t)(kb + t) * HID + j0;
            #pragma unroll
            for (int q = 0; q < 5; ++q) {
                const float4 w = *reinterpret_cast<const float4*>(wrow + q * 4);
                acc[q * 4 + 0] = fmaf(av, w.x, acc[q * 4 + 0]);
                acc[q * 4 + 1] = fmaf(av, w.y, acc[q * 4 + 1]);
                acc[q * 4 + 2] = fmaf(av, w.z, acc[q * 4 + 2]);
                acc[q * 4 + 3] = fmaf(av, w.w, acc[q * 4 + 3]);
            }
        }
    }

    if (row < N_NODES) {
        float* op = Xo + (size_t)row * HID + j0;
        #pragma unroll
        for (int q = 0; q < 5; ++q)
            *reinterpret_cast<float4*>(op + q * 4) =
                make_float4(acc[q * 4 + 0], acc[q * 4 + 1], acc[q * 4 + 2], acc[q * 4 + 3]);
    }
}

// ---------------- per-node online-softmax aggregation ----------------
// one wave per node; 4 edge slots x 16 lanes; lane u owns channels u*5..u*5+4
// (head h = u>>1). Head logit closed with shfl_xor(1); slots merged flash-style.

__global__ __launch_bounds__(256) void agg_k(const float* __restrict__ xl,
                                             const float* __restrict__ xr,
                                             const int* __restrict__ rowptr,
                                             const int* __restrict__ csr,
                                             const float* __restrict__ att,
                                             const float* __restrict__ bias,
                                             float* __restrict__ out) {
    const int tid = threadIdx.x;
    const int lane = tid & 63;
    const int node = blockIdx.x * 4 + (tid >> 6);
    if (node >= N_NODES) return;
    const int g = lane >> 4;
    const int u = lane & 15;
    const int cb = u * 5;

    float att5[5], xr5[5];
    #pragma unroll
    for (int c = 0; c < 5; ++c) {
        att5[c] = att[cb + c];
        xr5[c] = xr[(size_t)node * HID + cb + c];
    }
    const int ro = rowptr[node];
    const int deg = rowptr[node + 1] - ro;

    float m = -INFINITY, s = 0.f;
    float acc[5] = {0.f, 0.f, 0.f, 0.f, 0.f};

    for (int i = g; i < deg; i += 4) {
        const int src = csr[ro + i];
        const float* xlp = xl + (size_t)src * HID + cb;
        float xl5[5];
        float part = 0.f;
        #pragma unroll
        for (int c = 0; c < 5; ++c) {
            xl5[c] = xlp[c];
            float e = xl5[c] + xr5[c];
            e = (e > 0.f) ? e : NEG_SLOPE * e;
            part = fmaf(e, att5[c], part);
        }
        const float logit = part + __shfl_xor(part, 1, 64);
        const float nm = fmaxf(m, logit);
        const float scale = __expf(m - nm);      // m=-inf -> 0
        const float p = __expf(logit - nm);
        s = s * scale + p;
        #pragma unroll
        for (int c = 0; c < 5; ++c) acc[c] = acc[c] * scale + p * xl5[c];
        m = nm;
    }

    // merge the 4 edge slots (flash-attention state merge)
    #pragma unroll
    for (int off = 16; off <= 32; off <<= 1) {
        const float om = __shfl_xor(m, off, 64);
        const float os = __shfl_xor(s, off, 64);
        float oacc[5];
        #pragma unroll
        for (int c = 0; c < 5; ++c) oacc[c] = __shfl_xor(acc[c], off, 64);
        const float nm = fmaxf(m, om);
        const float sc1 = (m == -INFINITY) ? 0.f : __expf(m - nm);
        const float sc2 = (om == -INFINITY) ? 0.f : __expf(om - nm);
        s = s * sc1 + os * sc2;
        #pragma unroll
        for (int c = 0; c < 5; ++c) acc[c] = acc[c] * sc1 + oacc[c] * sc2;
        m = nm;
    }

    if (g == 0) {
        const float inv = 1.f / (s + 1e-16f);
        #pragma unroll
        for (int c = 0; c < 5; ++c) {
            float v = acc[c] * inv + bias[cb + c];
            v = (v > 0.f) ? v : (__expf(v) - 1.f);   // ELU
            out[(size_t)node * HID + cb + c] = v;
        }
    }
}

// ---------------- launch ----------------

extern "C" void kernel_launch(void* const* d_in, const int* in_sizes, int n_in,
                              void* d_out, int out_size, void* d_ws, size_t ws_size,
                              hipStream_t stream) {
    const float* x  = (const float*)d_in[0];
    const int*   ei = (const int*)d_in[1];
    const float* Wl[3]   = {(const float*)d_in[2], (const float*)d_in[6],  (const float*)d_in[10]};
    const float* Wr[3]   = {(const float*)d_in[3], (const float*)d_in[7],  (const float*)d_in[11]};
    const float* attp[3] = {(const float*)d_in[4], (const float*)d_in[8],  (const float*)d_in[12]};
    const float* bp[3]   = {(const float*)d_in[5], (const float*)d_in[9],  (const float*)d_in[13]};

    char* ws = (char*)d_ws;
    size_t off = 0;
    auto alloc = [&](size_t bytes) -> void* {
        void* p = ws + off;
        off += (bytes + 255) & ~(size_t)255;
        return p;
    };
    int* cnt    = (int*)alloc((size_t)N_NODES * 4);
    int* cursor = (int*)alloc((size_t)N_NODES * 4);
    int* rowptr = (int*)alloc((size_t)(N_NODES + 1) * 4);
    int* csr    = (int*)alloc((size_t)E_TOT * 4);
    float* xl   = (float*)alloc((size_t)N_NODES * HID * 4);
    float* xr   = (float*)alloc((size_t)N_NODES * HID * 4);
    float* actA = (float*)alloc((size_t)N_NODES * HID * 4);
    float* actB = (float*)alloc((size_t)N_NODES * HID * 4);

    hipMemsetAsync(cnt, 0, (size_t)N_NODES * 4, stream);
    hipMemsetAsync(cursor, 0, (size_t)N_NODES * 4, stream);

    hist_k<<<(E_TOT + 255) / 256, 256, 0, stream>>>(ei, cnt);
    scan_k<<<1, 1024, 0, stream>>>(cnt, rowptr);
    scatter_k<<<(E_TOT + 255) / 256, 256, 0, stream>>>(ei, rowptr, cursor, csr);

    for (int l = 0; l < 3; ++l) {
        const float* act_in = (l == 0) ? x : (l == 1 ? actA : actB);
        const int K = (l == 0) ? 256 : 80;
        gemm2_k<<<1564, 256, 0, stream>>>(act_in, K, Wl[l], Wr[l], xl, xr);
        float* out_l = (l == 0) ? actA : (l == 1 ? actB : (float*)d_out);
        agg_k<<<N_NODES / 4, 256, 0, stream>>>(xl, xr, rowptr, csr, attp[l], bp[l], out_l);
    }
}